// Round 10
// baseline (67.433 us; speedup 1.0000x reference)
//
#include <hip/hip_runtime.h>
#include <hip/hip_bf16.h>

#define TWO_N 8192
#define NHALF 4096
#define D 256
#define NT256 32            // 8192 / 256 tiles per dimension
#define BLK_ELEMS 32768     // 32 kchunks * 128 rows * 8 elems per 128-row block
static constexpr float INV_T = 2.0f; // 1 / 0.5

typedef __attribute__((ext_vector_type(8))) short short8;
typedef __attribute__((ext_vector_type(4))) float f32x4;

#define AS1 __attribute__((address_space(1)))
#define AS3 __attribute__((address_space(3)))

__device__ __forceinline__ ushort f2bfu(float f) {
    __hip_bfloat16 b = __float2bfloat16(f);
    return *reinterpret_cast<ushort*>(&b);
}

// ------ kernel 1: fused normalize + positive-pair sim, blocked-K-major out --
// znb layout: [rowblock(64)][kchunk(32)][row-in-block(128)][elem(8)]
//   flat = ((row>>7)*32 + (col>>3))*1024 + (row&127)*8 + (col&7)
__global__ __launch_bounds__(256) void norm_pos_kernel(
        const float* __restrict__ z_i, const float* __restrict__ z_j,
        ushort* __restrict__ znb, float* __restrict__ sim_pos,
        float* __restrict__ denom) {
    const int wid = threadIdx.x >> 6, lane = threadIdx.x & 63;
    const int i = blockIdx.x * 4 + wid;  // 0..4095
    const float4 vi = *reinterpret_cast<const float4*>(z_i + (size_t)i * D + lane * 4);
    const float4 vj = *reinterpret_cast<const float4*>(z_j + (size_t)i * D + lane * 4);
    float ssi = vi.x * vi.x + vi.y * vi.y + vi.z * vi.z + vi.w * vi.w;
    float ssj = vj.x * vj.x + vj.y * vj.y + vj.z * vj.z + vj.w * vj.w;
    float dt  = vi.x * vj.x + vi.y * vj.y + vi.z * vj.z + vi.w * vj.w;
    #pragma unroll
    for (int off = 32; off; off >>= 1) {
        ssi += __shfl_xor(ssi, off);
        ssj += __shfl_xor(ssj, off);
        dt  += __shfl_xor(dt,  off);
    }
    const float ri = rsqrtf(ssi), rj = rsqrtf(ssj);
    ushort4 oi, oj;
    oi.x = f2bfu(vi.x * ri); oi.y = f2bfu(vi.y * ri);
    oi.z = f2bfu(vi.z * ri); oi.w = f2bfu(vi.w * ri);
    oj.x = f2bfu(vj.x * rj); oj.y = f2bfu(vj.y * rj);
    oj.z = f2bfu(vj.z * rj); oj.w = f2bfu(vj.w * rj);
    const int c = lane >> 1, e = (lane & 1) * 4;
    const int i2 = i + NHALF;
    const size_t bi = ((size_t)(i  >> 7) * 32 + c) * 1024 + (i  & 127) * 8 + e;
    const size_t bj = ((size_t)(i2 >> 7) * 32 + c) * 1024 + (i2 & 127) * 8 + e;
    *reinterpret_cast<ushort4*>(znb + bi) = oi;
    *reinterpret_cast<ushort4*>(znb + bj) = oj;
    if (lane == 0) {
        const float sp = dt * ri * rj * INV_T;
        sim_pos[i] = sp;
        sim_pos[i + NHALF] = sp;   // symmetric
        denom[i] = 0.0f;
        denom[i + NHALF] = 0.0f;
    }
}

// ------ kernel 2: 256x256-tile symmetric sim-GEMM + exp + row/col sums ------
// 8 waves (2M x 4N), per-wave 128x64 output (M_rep=8, N_rep=4), BK=32,
// mfma_f32_16x16x32_bf16. R7's proven ring-3 counted-vmcnt schedule scaled up:
//   prologue: STAGE(0), STAGE(1)      // 8 loads/thread in flight
//   iter ks:  vmcnt(4) -> barrier -> STAGE((ks+2)%3) -> ds_read -> 32 MFMA
// LDS: 3 bufs x (A 16KB + B 16KB) = 96 KB. Per buf: [rb(2)][kc(4)][row(128)][8]
// staged from 4 contiguous 8 KB regions of the blocked layout (coalesced,
// linear dests, conflict-free ds_read_b128 -- all verified in R3/R7).
__global__ __launch_bounds__(512, 2) void gemm_denom_kernel(
        const ushort* __restrict__ znb, float* __restrict__ denom) {
    const int tr = blockIdx.x;
    const int tc = blockIdx.y;
    if (tc < tr) return;  // block-uniform exit before any sync

    __shared__ ushort As[3][8192];  // [buf][rb*4096 + kc*1024 + row*8 + e]
    __shared__ ushort Bs[3][8192];

    const int tid  = threadIdx.x;      // 0..511
    const int lane = tid & 63;
    const int wid  = tid >> 6;         // 0..7
    const int wr   = wid >> 2;         // M-wave 0..1 (128 rows each)
    const int wc   = wid & 3;          // N-wave 0..3 (64 cols each)
    const int r16  = lane & 15;
    const int kgrp = lane >> 4;        // 0..3
    const int row0 = tr * 256;
    const int col0 = tc * 256;

    // staging sources: chunk tid (16B) of each 8 KB region (rb 0/1 for A,B)
    const ushort* gA0 = znb + (size_t)(2 * tr) * BLK_ELEMS + tid * 8;
    const ushort* gA1 = gA0 + BLK_ELEMS;
    const ushort* gB0 = znb + (size_t)(2 * tc) * BLK_ELEMS + tid * 8;
    const ushort* gB1 = gB0 + BLK_ELEMS;
    const int dst = wid * 512;         // wave-uniform LDS dest (ushorts)

    #define STAGE(buf, koff)                                                      \
        do {                                                                      \
            __builtin_amdgcn_global_load_lds((const AS1 void*)(gA0 + (koff)),     \
                (AS3 void*)(As[buf] + dst), 16, 0, 0);                            \
            __builtin_amdgcn_global_load_lds((const AS1 void*)(gA1 + (koff)),     \
                (AS3 void*)(As[buf] + 4096 + dst), 16, 0, 0);                     \
            __builtin_amdgcn_global_load_lds((const AS1 void*)(gB0 + (koff)),     \
                (AS3 void*)(Bs[buf] + dst), 16, 0, 0);                            \
            __builtin_amdgcn_global_load_lds((const AS1 void*)(gB1 + (koff)),     \
                (AS3 void*)(Bs[buf] + 4096 + dst), 16, 0, 0);                     \
        } while (0)

    f32x4 acc[8][4];
    #pragma unroll
    for (int m = 0; m < 8; ++m)
        #pragma unroll
        for (int n = 0; n < 4; ++n) {
            f32x4 z = {0.f, 0.f, 0.f, 0.f};
            acc[m][n] = z;
        }

    STAGE(0, 0);
    STAGE(1, 4096);

    // per-wave LDS read bases (ushort offsets)
    const int aOff = wr * 4096 + kgrp * 1024 + r16 * 8;
    const int bOff = (wc >> 1) * 4096 + kgrp * 1024 + ((wc & 1) * 64 + r16) * 8;

    #pragma unroll
    for (int ks = 0; ks < 8; ++ks) {
        const int cur = ks % 3;
        // counted wait: stage(ks) landed; stage(ks+1) stays in flight (T4)
        if (ks < 7) asm volatile("s_waitcnt vmcnt(4)" ::: "memory");
        else        asm volatile("s_waitcnt vmcnt(0)" ::: "memory");
        __builtin_amdgcn_s_barrier();
        asm volatile("" ::: "memory");  // pin: no loads migrate above barrier
        if (ks < 6) STAGE((ks + 2) % 3, (ks + 2) * 4096);
        short8 a[8], b[4];
        #pragma unroll
        for (int m = 0; m < 8; ++m)
            a[m] = *reinterpret_cast<const short8*>(As[cur] + aOff + m * 128);
        #pragma unroll
        for (int n = 0; n < 4; ++n)
            b[n] = *reinterpret_cast<const short8*>(Bs[cur] + bOff + n * 128);
        #pragma unroll
        for (int m = 0; m < 8; ++m)
            #pragma unroll
            for (int n = 0; n < 4; ++n)
                acc[m][n] = __builtin_amdgcn_mfma_f32_16x16x32_bf16(
                    a[m], b[n], acc[m][n], 0, 0, 0);
    }
    #undef STAGE

    // ---- epilogue: exp, diag zero, row sums (+ col sums if off-diagonal) ----
    const bool offdiag = (tr != tc);
    float cs[4] = {0.f, 0.f, 0.f, 0.f};
    #pragma unroll
    for (int m = 0; m < 8; ++m) {
        #pragma unroll
        for (int reg = 0; reg < 4; ++reg) {
            const int rg = row0 + wr * 128 + m * 16 + kgrp * 4 + reg;
            float rs = 0.f;
            #pragma unroll
            for (int n = 0; n < 4; ++n) {
                const int cg = col0 + wc * 64 + n * 16 + r16;
                float e = __expf(acc[m][n][reg] * INV_T);
                if (rg == cg) e = 0.f;   // only possible when tr==tc
                rs += e;
                cs[n] += e;
            }
            rs += __shfl_xor(rs, 1);
            rs += __shfl_xor(rs, 2);
            rs += __shfl_xor(rs, 4);
            rs += __shfl_xor(rs, 8);
            if (r16 == 0) atomicAdd(&denom[rg], rs);
        }
    }
    if (offdiag) {
        #pragma unroll
        for (int n = 0; n < 4; ++n) {
            cs[n] += __shfl_xor(cs[n], 16);
            cs[n] += __shfl_xor(cs[n], 32);
        }
        if (kgrp == 0) {
            #pragma unroll
            for (int n = 0; n < 4; ++n)
                atomicAdd(&denom[col0 + wc * 64 + n * 16 + r16], cs[n]);
        }
    }
}

// ---------------- kernel 3: final loss reduction ----------------
__global__ __launch_bounds__(1024) void final_kernel(
        const float* __restrict__ sim_pos, const float* __restrict__ denom,
        float* __restrict__ out) {
    const int tid = threadIdx.x;
    float s = 0.f;
    for (int i = tid; i < TWO_N; i += 1024)
        s += sim_pos[i] - logf(denom[i]);
    #pragma unroll
    for (int off = 32; off; off >>= 1) s += __shfl_down(s, off);
    __shared__ float red[16];
    const int wid = tid >> 6, lane = tid & 63;
    if (lane == 0) red[wid] = s;
    __syncthreads();
    if (tid == 0) {
        float t = 0.f;
        #pragma unroll
        for (int w = 0; w < 16; ++w) t += red[w];
        out[0] = -t / (float)TWO_N;
    }
}

extern "C" void kernel_launch(void* const* d_in, const int* in_sizes, int n_in,
                              void* d_out, int out_size, void* d_ws, size_t ws_size,
                              hipStream_t stream) {
    const float* z_i = (const float*)d_in[0];
    const float* z_j = (const float*)d_in[1];
    float* out = (float*)d_out;

    ushort* znb     = (ushort*)d_ws;                                  // 4 MB
    float*  sim_pos = (float*)((char*)d_ws + (size_t)TWO_N * D * 2);  // 32 KB
    float*  denom   = sim_pos + TWO_N;                                // 32 KB

    norm_pos_kernel<<<NHALF / 4, 256, 0, stream>>>(z_i, z_j, znb, sim_pos, denom);
    dim3 grid(NT256, NT256);
    gemm_denom_kernel<<<grid, 512, 0, stream>>>(znb, denom);
    final_kernel<<<1, 1024, 0, stream>>>(sim_pos, denom, out);
}